// Round 10
// baseline (467.212 us; speedup 1.0000x reference)
//
#include <hip/hip_runtime.h>
#include <hip/hip_bf16.h>

#define DEV __device__ __forceinline__

typedef __attribute__((ext_vector_type(8))) short bf16x8;
typedef __attribute__((ext_vector_type(4))) float f32x4;
typedef __attribute__((ext_vector_type(8))) unsigned short u16x8;

DEV unsigned short f2bf(float f){
  unsigned int b = __float_as_uint(f);
  return (unsigned short)((b + 0x7fffu + ((b >> 16) & 1u)) >> 16);
}
DEV float bf2f(unsigned short u){ return __uint_as_float(((unsigned int)u)<<16); }

DEV float silu_f(float v){ return v / (1.f + __expf(-v)); }

DEV void gl_lds16(const void* g, void* l){
  __builtin_amdgcn_global_load_lds((const __attribute__((address_space(1))) void*)g,
                                   (__attribute__((address_space(3))) void*)l, 16, 0, 0);
}

// ---------- prep_ln: LN (4 rows/blk) + weight transposes + bias + embgemm -----
// [0,8192): x-LN ; [8192,10240): xf-LN ; [10240,10248): bias concat ;
// [10248,13832): weight tiles (3584) ; [13832,13960): embgemm k-split (128)
DEV void wtile(const float* W, unsigned short* Wt, int K, int N, int nt, int kt, int tid,
               float (*tile)[33])
{
  int n0 = nt<<5, k0 = kt<<5;
  int tx = tid & 31, ty = tid >> 5;
  #pragma unroll
  for (int i=0;i<4;i++)
    tile[ty + i*8][tx] = W[(size_t)(k0 + ty + i*8)*N + n0 + tx];
  __syncthreads();
  #pragma unroll
  for (int i=0;i<4;i++)
    Wt[(size_t)(n0 + ty + i*8)*K + k0 + tx] = f2bf(tile[tx][ty + i*8]);
}

__global__ __launch_bounds__(256) void prep_ln(
    const float* __restrict__ x, const float* __restrict__ xf,
    const float* __restrict__ gx, const float* __restrict__ bx_,
    const float* __restrict__ gt, const float* __restrict__ bt,
    unsigned short* __restrict__ ox, unsigned short* __restrict__ ot,
    const float* __restrict__ Wq, const float* __restrict__ Wk,
    const float* __restrict__ Wv, const float* __restrict__ Wo,
    const float* __restrict__ bk, const float* __restrict__ bv,
    unsigned short* __restrict__ wqt, unsigned short* __restrict__ wkvt,
    unsigned short* __restrict__ wot, float* __restrict__ bkv,
    const float* __restrict__ emb, const float* __restrict__ We,
    float* __restrict__ epart)
{
  __shared__ float shbuf[4096];   // 16KB: LN red[32] / tile[32][33] / a[32][128]
  int blk = blockIdx.x, t = threadIdx.x;
  if (blk >= 10240){
    int id = blk - 10240;
    if (id < 8){
      int i = id*256 + t;
      bkv[i] = (i < 1024) ? bk[i] : bv[i-1024];
      return;
    }
    id -= 8;
    if (id < 3584){
      float (*tile)[33] = (float(*)[33])shbuf;
      if (id < 1024){ wtile(Wq, wqt, 1024, 1024, id & 31, id >> 5, t, tile); return; }
      id -= 1024;
      if (id < 768){ wtile(Wk, wkvt, 768, 1024, id & 31, id >> 5, t, tile); return; }
      id -= 768;
      if (id < 768){ wtile(Wv, wkvt + (size_t)1024*768, 768, 1024, id & 31, id >> 5, t, tile); return; }
      id -= 768;
      wtile(Wo, wot, 1024, 1024, id & 31, id >> 5, t, tile);
      return;
    }
    id -= 3584;   // embgemm: 128 blocks, cb = id&7, ks = id>>3
    float (*a)[128] = (float(*)[128])shbuf;
    int cb = id & 7, ks = id >> 3;
    int k0 = ks << 7;
    #pragma unroll
    for (int it=0; it<4; ++it){
      int fi = it*256 + t;
      int r = fi>>5, c4 = (fi&31)<<2;
      float4 vv = *(const float4*)(emb + (size_t)r*2048 + k0 + c4);
      vv.x = silu_f(vv.x); vv.y = silu_f(vv.y); vv.z = silu_f(vv.z); vv.w = silu_f(vv.w);
      *(float4*)&a[r][c4] = vv;
    }
    __syncthreads();
    int c0 = (cb<<8) + t;
    float accv[32];
    #pragma unroll
    for (int r=0;r<32;r++) accv[r]=0.f;
    #pragma unroll 4
    for (int kk=0;kk<128;kk++){
      float wv = We[(size_t)(k0+kk)*2048 + c0];
      #pragma unroll
      for (int r=0;r<32;r++) accv[r] += a[r][kk]*wv;
    }
    #pragma unroll
    for (int r=0;r<32;r++) epart[(size_t)(ks*32 + r)*2048 + c0] = accv[r];
    return;
  }
  // LN, 4 consecutive rows per block
  const float* src; const float* g; const float* bb; unsigned short* out;
  int D, nvec;
  if (blk < 8192){
    int r0 = blk<<2;
    src = x + (size_t)r0*1024; g = gx; bb = bx_; out = ox + (size_t)r0*1024; D = 1024; nvec = 256;
  } else {
    int r0 = (blk-8192)<<2;
    src = xf + (size_t)r0*768; g = gt; bb = bt; out = ot + (size_t)r0*768; D = 768; nvec = 192;
  }
  float4 v[4];
  float s[4], s2[4];
  #pragma unroll
  for (int r=0;r<4;r++){
    v[r] = make_float4(0.f,0.f,0.f,0.f);
    if (t < nvec) v[r] = ((const float4*)(src + (size_t)r*D))[t];
    s[r]  = v[r].x+v[r].y+v[r].z+v[r].w;
    s2[r] = v[r].x*v[r].x+v[r].y*v[r].y+v[r].z*v[r].z+v[r].w*v[r].w;
  }
  #pragma unroll
  for (int o=32;o;o>>=1){
    #pragma unroll
    for (int r=0;r<4;r++){
      s[r]  += __shfl_down(s[r], o, 64);
      s2[r] += __shfl_down(s2[r], o, 64);
    }
  }
  int w = t>>6;
  if ((t&63)==0){
    #pragma unroll
    for (int r=0;r<4;r++){ shbuf[w*4+r] = s[r]; shbuf[16+w*4+r] = s2[r]; }
  }
  __syncthreads();
  float4 gv = make_float4(0.f,0.f,0.f,0.f), bv4 = make_float4(0.f,0.f,0.f,0.f);
  if (t < nvec){ gv = ((const float4*)g)[t]; bv4 = ((const float4*)bb)[t]; }
  float invD = 1.f/(float)D;
  #pragma unroll
  for (int r=0;r<4;r++){
    float fs  = shbuf[r] + shbuf[4+r] + shbuf[8+r] + shbuf[12+r];
    float fs2 = shbuf[16+r] + shbuf[20+r] + shbuf[24+r] + shbuf[28+r];
    float mean = fs*invD;
    float var  = fmaxf(fs2*invD - mean*mean, 0.f);
    float rstd = rsqrtf(var + 1e-5f);
    if (t < nvec){
      ushort4 o4;
      o4.x = f2bf((v[r].x-mean)*rstd*gv.x + bv4.x);
      o4.y = f2bf((v[r].y-mean)*rstd*gv.y + bv4.y);
      o4.z = f2bf((v[r].z-mean)*rstd*gv.z + bv4.z);
      o4.w = f2bf((v[r].w-mean)*rstd*gv.w + bv4.w);
      *(ushort4*)(out + (size_t)r*D + t*4) = o4;
    }
  }
}

// ---------------- GEMM body: round-2 structure (128x128, BK=64, dbuf 64KB) ----
// EPI: 0 = bf16 C. 1 = fp32 C = Xadd + val. 2 = KV fused: N [0,1024) -> K bf16;
//      N [1024,2048) -> V into pre-swizzled vt blocks.
template<int EPI>
DEV void gemm_body(
  const unsigned char* __restrict__ A, const unsigned char* __restrict__ Wt,
  const float* __restrict__ bias, void* __restrict__ Cout,
  const float* __restrict__ Xadd, unsigned char* __restrict__ vt,
  int M, int N, int K, int bx, int by, unsigned char* lds)
{
  const int tid = threadIdx.x, w = tid>>6, lane = tid&63;
  const int l15 = lane&15, lq = lane>>4;
  const int m0 = by<<7, n0 = bx<<7;
  const size_t K2 = (size_t)K<<1;
  const int KT = K>>6;
  const int wr = (w>>1)&1, wc = w&1;
  const int srow = lane>>3;
  const int scb  = (lane&7)<<4;

  f32x4 acc[4][4];
  f32x4 zero = {0.f,0.f,0.f,0.f};
  #pragma unroll
  for (int i=0;i<4;i++)
    #pragma unroll
    for (int j=0;j<4;j++) acc[i][j] = zero;

  auto stage = [&](int buf, int kt){
    unsigned char* ldsA = lds + buf*32768;
    const size_t kb = (size_t)kt<<7;
    #pragma unroll
    for (int inst=0; inst<4; ++inst){
      int base = w*1024 + inst*4096;
      int row  = (base>>7) + srow;
      int cs   = scb ^ ((row&7)<<4);
      gl_lds16(A  + (size_t)(m0+row)*K2 + kb + cs, ldsA + base);
      gl_lds16(Wt + (size_t)(n0+row)*K2 + kb + cs, ldsA + 16384 + base);
    }
  };

  stage(0, 0);
  __syncthreads();
  for (int kt=0; kt<KT; ++kt){
    if (kt+1 < KT) stage((kt+1)&1, kt+1);
    const unsigned char* ldsA = lds + (kt&1)*32768;
    const unsigned char* ldsB = ldsA + 16384;
    bf16x8 af[2][4], bfr[2][4];
    #pragma unroll
    for (int i=0;i<4;i++){
      int r = wr*64 + i*16 + l15;
      int rb = r<<7, sw = (r&7)<<4;
      af[0][i] = *(const bf16x8*)(ldsA + rb + ((lq*16) ^ sw));
      af[1][i] = *(const bf16x8*)(ldsA + rb + ((64 + lq*16) ^ sw));
    }
    #pragma unroll
    for (int j=0;j<4;j++){
      int r = wc*64 + j*16 + l15;
      int rb = r<<7, sw = (r&7)<<4;
      bfr[0][j] = *(const bf16x8*)(ldsB + rb + ((lq*16) ^ sw));
      bfr[1][j] = *(const bf16x8*)(ldsB + rb + ((64 + lq*16) ^ sw));
    }
    #pragma unroll
    for (int kc=0;kc<2;kc++)
      #pragma unroll
      for (int i=0;i<4;i++)
        #pragma unroll
        for (int j=0;j<4;j++)
          acc[i][j] = __builtin_amdgcn_mfma_f32_16x16x32_bf16(af[kc][i], bfr[kc][j], acc[i][j], 0,0,0);
    __syncthreads();
  }
  #pragma unroll
  for (int j=0;j<4;j++){
    int n = n0 + wc*64 + j*16 + l15;
    float bvs = bias[n];
    #pragma unroll
    for (int i=0;i<4;i++){
      int mb = m0 + wr*64 + i*16 + lq*4;
      #pragma unroll
      for (int r=0;r<4;r++){
        int m = mb + r;
        float val = acc[i][j][r] + bvs;
        if (EPI==0){
          ((unsigned short*)Cout)[(size_t)m*N + n] = f2bf(val);
        } else if (EPI==1){
          size_t idx = (size_t)m*N + n;
          ((float*)Cout)[idx] = Xadd[idx] + val;
        } else {
          if (n0 < 1024){
            ((unsigned short*)Cout)[(size_t)m*1024 + n] = f2bf(val);
          } else {
            int d  = (n-1024)&63;
            int hh = (n-1024)>>6;
            int bb_ = m>>8, nk = m&255;
            *(unsigned short*)(vt + ((size_t)(bb_*16+hh)<<15) + d*512
                + (((nk>>3)<<4) ^ ((d&7)<<4)) + ((nk&7)<<1)) = f2bf(val);
          }
        }
      }
    }
  }
}

// ---------------- merged QKV projections (with dead-batch skip) ----------------
// [0,2048): Q-proj (EPI0, batch = by>>3). [2048,3072): KV-proj (EPI2, batch = by>>1).
__global__ __launch_bounds__(256,2) void qkv(
  const unsigned char* __restrict__ xln, const unsigned char* __restrict__ wqt,
  const float* __restrict__ bq, unsigned char* __restrict__ qb,
  const unsigned char* __restrict__ xfn, const unsigned char* __restrict__ wkvt,
  const float* __restrict__ bkv, unsigned char* __restrict__ kb,
  unsigned char* __restrict__ vtb, const int* __restrict__ cond)
{
  __shared__ __align__(16) unsigned char lds[65536];
  int wg = blockIdx.x;
  if (wg < 2048){
    int lg = (wg & 7) * 256 + (wg >> 3);
    int by = lg >> 3;
    if (cond[by >> 3] % 10 == 0) return;   // dead batch: q never read
    gemm_body<0>(xln, wqt, bq, qb, nullptr, nullptr, 32768, 1024, 1024, lg & 7, by, lds);
  } else {
    int w2 = wg - 2048;
    int lg = (w2 & 7) * 128 + (w2 >> 3);
    int by = lg >> 4;
    if (cond[by >> 1] % 10 == 0) return;   // dead batch: k/v never read
    gemm_body<2>(xfn, wkvt, bkv, kb, nullptr, vtb, 8192, 2048, 768, lg & 15, by, lds);
  }
}

// ---------------- fused cross-attention + embred tail --------------------------
// [0,8192): attention blocks. [8192,8224): embred (eo = sum epart + be).
__global__ __launch_bounds__(256,2) void attn64(
  const unsigned char* __restrict__ qg, const unsigned char* __restrict__ kg,
  int kstride, const unsigned char* __restrict__ vtg, const int* __restrict__ cond,
  unsigned short* __restrict__ yout,
  const float* __restrict__ epart, const float* __restrict__ be,
  float* __restrict__ eo)
{
  __shared__ __align__(16) unsigned char lds[73728];
  const int wg = blockIdx.x;
  const int tid = threadIdx.x;
  if (wg >= 8192){
    int idx0 = (wg - 8192) * 2048 + tid;
    #pragma unroll
    for (int e=0;e<8;e++){
      int idx = idx0 + e*256;
      float s = be[idx & 2047];
      #pragma unroll
      for (int ks=0;ks<16;ks++) s += epart[(size_t)ks*65536 + idx];
      eo[idx] = s;
    }
    return;
  }
  const int lg = (wg & 7) * 1024 + (wg >> 3);
  const int t0 = (lg & 15) * 64;
  const int h  = (lg >> 4) & 15;
  const int b  = lg >> 8;
  const int w = tid>>6, lane = tid&63;
  const int l15 = lane&15, lq = lane>>4;

  if (cond[b] % 10 == 0){
    int row = t0 + (tid>>2);
    unsigned short* dst = yout + (size_t)(b*1024 + row)*1024 + h*64 + (tid&3)*16;
    u16x8 z = {0,0,0,0,0,0,0,0};
    *(u16x8*)dst = z;
    *(u16x8*)(dst + 8) = z;
    return;
  }

  const unsigned char* kbase = kg + (size_t)b*256*kstride + (size_t)h*128;
  const unsigned char* vtb   = vtg + (size_t)(b*16+h)*32768;
  #pragma unroll
  for (int i=0;i<8;i++){
    int base = (w*8+i)*1024;
    int n  = (base>>7) + (lane>>3);
    int cb = (lane&7)<<4;
    gl_lds16(kbase + (size_t)n*kstride + (cb ^ ((n&7)<<4)), lds + base);
    gl_lds16(vtb + base + lane*16, lds + 32768 + base);
  }
  const unsigned char* qbase = qg + (size_t)(b*1024 + t0)*2048 + h*128;
  #pragma unroll
  for (int i=0;i<2;i++){
    int row = i*32 + (tid>>3);
    int cs  = ((tid&7)<<4) ^ ((row&7)<<4);
    gl_lds16(qbase + (size_t)row*2048 + cs, lds + 65536 + i*4096 + w*1024);
  }
  __syncthreads();

  const int qr = w*16 + l15;
  const int qsw = (qr&7)<<4;
  bf16x8 aq0 = *(const bf16x8*)(lds + 65536 + qr*128 + ((lq*16) ^ qsw));
  bf16x8 aq1 = *(const bf16x8*)(lds + 65536 + qr*128 + ((64 + lq*16) ^ qsw));

  f32x4 zero = {0.f,0.f,0.f,0.f};
  f32x4 s[16];
  #pragma unroll
  for (int nt=0;nt<16;nt++) s[nt] = zero;
  #pragma unroll
  for (int nt=0;nt<16;nt++){
    int n = nt*16 + l15;
    int rb = n<<7, sw = (n&7)<<4;
    bf16x8 kb0 = *(const bf16x8*)(lds + rb + ((lq*16) ^ sw));
    bf16x8 kb1 = *(const bf16x8*)(lds + rb + ((64 + lq*16) ^ sw));
    s[nt] = __builtin_amdgcn_mfma_f32_16x16x32_bf16(aq0, kb0, s[nt], 0,0,0);
    s[nt] = __builtin_amdgcn_mfma_f32_16x16x32_bf16(aq1, kb1, s[nt], 0,0,0);
  }
  #pragma unroll
  for (int r=0;r<4;r++){
    float m = s[0][r];
    #pragma unroll
    for (int nt=1;nt<16;nt++) m = fmaxf(m, s[nt][r]);
    m = fmaxf(m, __shfl_xor(m,1,64));
    m = fmaxf(m, __shfl_xor(m,2,64));
    m = fmaxf(m, __shfl_xor(m,4,64));
    m = fmaxf(m, __shfl_xor(m,8,64));
    float sum = 0.f;
    #pragma unroll
    for (int nt=0;nt<16;nt++){ float p = __expf(s[nt][r]-m); s[nt][r]=p; sum+=p; }
    sum += __shfl_xor(sum,1,64);
    sum += __shfl_xor(sum,2,64);
    sum += __shfl_xor(sum,4,64);
    sum += __shfl_xor(sum,8,64);
    float inv = 1.f/sum;
    #pragma unroll
    for (int nt=0;nt<16;nt++) s[nt][r] *= inv;
  }
  __syncthreads();
  #pragma unroll
  for (int nt=0;nt<16;nt++){
    int n = nt*16 + l15;
    int nb = (n>>3)<<4, nr = (n&7)<<1;
    #pragma unroll
    for (int r=0;r<4;r++){
      int tl = w*16 + lq*4 + r;
      *(unsigned short*)(lds + tl*512 + ((nb ^ ((tl&7)<<4)) | nr)) = f2bf(s[nt][r]);
    }
  }
  __syncthreads();
  f32x4 yv[4];
  #pragma unroll
  for (int dt=0;dt<4;dt++) yv[dt] = zero;
  const int tl = w*16 + l15;
  const int swp = (tl&7)<<4;
  #pragma unroll
  for (int kc=0;kc<8;kc++){
    bf16x8 pa = *(const bf16x8*)(lds + tl*512 + ((kc*64 + lq*16) ^ swp));
    #pragma unroll
    for (int dt=0;dt<4;dt++){
      int d = dt*16 + l15;
      bf16x8 vbv = *(const bf16x8*)(lds + 32768 + d*512 + ((kc*64 + lq*16) ^ ((d&7)<<4)));
      yv[dt] = __builtin_amdgcn_mfma_f32_16x16x32_bf16(pa, vbv, yv[dt], 0,0,0);
    }
  }
  #pragma unroll
  for (int dt=0;dt<4;dt++){
    #pragma unroll
    for (int r=0;r<4;r++){
      int tt = t0 + w*16 + lq*4 + r;
      yout[(size_t)(b*1024 + tt)*1024 + h*64 + dt*16 + l15] = f2bf(yv[dt][r]);
    }
  }
}

// ---------------- stylization --------------------------------------------------
__global__ __launch_bounds__(256) void styl(const unsigned short* __restrict__ y,
    const float* __restrict__ g, const float* __restrict__ bt,
    const float* __restrict__ eo, unsigned short* __restrict__ hout)
{
  int row = blockIdx.x, t = threadIdx.x, b = row>>10;
  ushort4 yv4 = ((const ushort4*)(y + (size_t)row*1024))[t];
  float in[4] = {bf2f(yv4.x), bf2f(yv4.y), bf2f(yv4.z), bf2f(yv4.w)};
  float s  = in[0]+in[1]+in[2]+in[3];
  float s2 = in[0]*in[0]+in[1]*in[1]+in[2]*in[2]+in[3]*in[3];
  #pragma unroll
  for (int o=32;o;o>>=1){ s += __shfl_down(s,o,64); s2 += __shfl_down(s2,o,64); }
  __shared__ float red[8];
  if ((t&63)==0){ red[t>>6]=s; red[4+(t>>6)]=s2; }
  __syncthreads();
  float fs  = red[0]+red[1]+red[2]+red[3];
  float fs2 = red[4]+red[5]+red[6]+red[7];
  float mean = fs*(1.f/1024.f);
  float var  = fmaxf(fs2*(1.f/1024.f) - mean*mean, 0.f);
  float rstd = rsqrtf(var + 1e-5f);
  float4 gv = ((const float4*)g)[t];
  float4 bv = ((const float4*)bt)[t];
  float4 sc = ((const float4*)(eo + (size_t)b*2048))[t];
  float4 sh = ((const float4*)(eo + (size_t)b*2048 + 1024))[t];
  float gg[4]  = {gv.x,gv.y,gv.z,gv.w};
  float bb[4]  = {bv.x,bv.y,bv.z,bv.w};
  float scs[4] = {sc.x,sc.y,sc.z,sc.w};
  float shs[4] = {sh.x,sh.y,sh.z,sh.w};
  unsigned short oo[4];
  #pragma unroll
  for (int c=0;c<4;c++){
    float hv = (in[c]-mean)*rstd*gg[c] + bb[c];
    hv = hv*(1.f+scs[c]) + shs[c];
    oo[c] = f2bf(silu_f(hv));
  }
  ushort4 o4; o4.x=oo[0]; o4.y=oo[1]; o4.z=oo[2]; o4.w=oo[3];
  *(ushort4*)(hout + (size_t)row*1024 + t*4) = o4;
}

// ---------------- O-projection + residual --------------------------------------
__global__ __launch_bounds__(256,2) void gemmO(
  const unsigned char* __restrict__ A, const unsigned char* __restrict__ Wt,
  const float* __restrict__ bias, float* __restrict__ Cout,
  const float* __restrict__ Xadd)
{
  __shared__ __align__(16) unsigned char lds[65536];
  int wg = blockIdx.x;
  int lg = (wg & 7) * 256 + (wg >> 3);
  gemm_body<1>(A, Wt, bias, Cout, Xadd, nullptr, 32768, 1024, 1024, lg & 7, lg >> 3, lds);
}

// ---------------- launcher ----------------------------------------------------
extern "C" void kernel_launch(void* const* d_in, const int* in_sizes, int n_in,
                              void* d_out, int out_size, void* d_ws, size_t ws_size,
                              hipStream_t stream) {
  const float* x      = (const float*)d_in[0];
  const float* xf     = (const float*)d_in[1];
  const float* emb    = (const float*)d_in[2];
  const int*   cond   = (const int*)d_in[4];
  const float* ln_x_g = (const float*)d_in[5];
  const float* ln_x_b = (const float*)d_in[6];
  const float* ln_t_g = (const float*)d_in[7];
  const float* ln_t_b = (const float*)d_in[8];
  const float* Wq     = (const float*)d_in[9];
  const float* bq     = (const float*)d_in[10];
  const float* Wk     = (const float*)d_in[11];
  const float* bk     = (const float*)d_in[12];
  const float* Wv     = (const float*)d_in[13];
  const float* bv     = (const float*)d_in[14];
  const float* We     = (const float*)d_in[15];
  const float* be     = (const float*)d_in[16];
  const float* ln_y_g = (const float*)d_in[17];
  const float* ln_y_b = (const float*)d_in[18];
  const float* Wo     = (const float*)d_in[19];
  const float* bo     = (const float*)d_in[20];
  float* out = (float*)d_out;

  unsigned char* ws = (unsigned char*)d_ws;
  size_t off = 0;
  auto take = [&](size_t n){ unsigned char* p = ws + off; off += (n + 255) & ~(size_t)255; return p; };
  unsigned char* r1    = take(67108864);   // xln bf16 -> h bf16
  unsigned char* qb    = take(67108864);   // q bf16 -> y bf16 (in place)
  unsigned char* xfn   = take(12582912);   // LN(xf) bf16
  unsigned char* kb    = take(16777216);   // k bf16 [8192][1024]
  unsigned char* vtb   = take(16777216);   // v^T pre-swizzled bf16
  unsigned char* wqt   = take(2097152);
  unsigned char* wkvt  = take(3145728);
  unsigned char* wot   = take(2097152);
  unsigned char* eo    = take(262144);
  unsigned char* bkv   = take(8192);
  unsigned char* epart = take(4194304);    // [16][32][2048] fp32

  dim3 blk(256);
  // 1) LN (4 rows/block) + weight prep + embgemm
  prep_ln<<<13960, blk, 0, stream>>>(x, xf, ln_x_g, ln_x_b, ln_t_g, ln_t_b,
      (unsigned short*)r1, (unsigned short*)xfn,
      Wq, Wk, Wv, Wo, bk, bv,
      (unsigned short*)wqt, (unsigned short*)wkvt, (unsigned short*)wot, (float*)bkv,
      emb, We, (float*)epart);
  // 2) Q-proj + KV-proj (fused V->vt), dead-batch skip, exactly 6 occupancy-waves
  qkv<<<3072, blk, 0, stream>>>(r1, wqt, bq, qb,
      xfn, wkvt, (const float*)bkv, kb, vtb, cond);
  // 3) attention (y bf16 in place over q) + embred tail
  attn64<<<8224, blk, 0, stream>>>(qb, kb, 2048, vtb, cond, (unsigned short*)qb,
      (const float*)epart, be, (float*)eo);
  // 4) stylization -> h bf16 (overwrites r1)
  styl<<<32768, blk, 0, stream>>>((const unsigned short*)qb, ln_y_g, ln_y_b, (const float*)eo, (unsigned short*)r1);
  // 5) O-projection + residual
  gemmO<<<2048, blk, 0, stream>>>(r1, wot, bo, out, x);
}

// Round 11
// 438.021 us; speedup vs baseline: 1.0666x; 1.0666x over previous
//
#include <hip/hip_runtime.h>
#include <hip/hip_bf16.h>

#define DEV __device__ __forceinline__

typedef __attribute__((ext_vector_type(8))) short bf16x8;
typedef __attribute__((ext_vector_type(4))) float f32x4;
typedef __attribute__((ext_vector_type(8))) unsigned short u16x8;

DEV unsigned short f2bf(float f){
  unsigned int b = __float_as_uint(f);
  return (unsigned short)((b + 0x7fffu + ((b >> 16) & 1u)) >> 16);
}
DEV float bf2f(unsigned short u){ return __uint_as_float(((unsigned int)u)<<16); }

DEV float silu_f(float v){ return v / (1.f + __expf(-v)); }

DEV void gl_lds16(const void* g, void* l){
  __builtin_amdgcn_global_load_lds((const __attribute__((address_space(1))) void*)g,
                                   (__attribute__((address_space(3))) void*)l, 16, 0, 0);
}

// ---------- prep_ln: LN (4 rows/blk) + weight transposes + bias concat --------
// [0,8192): x-LN ; [8192,10240): xf-LN ; [10240,10248): bias concat ;
// [10248,13832): weight tiles (3584).
// NOTE: embgemm deliberately NOT merged here — its accv[32]/a[32][128] footprint
// raises the whole kernel to 88 VGPR / 16KB LDS and cuts LN occupancy 26->16%
// (round-10 regression, 140us). Keep this kernel at 56 VGPR.
DEV void wtile(const float* W, unsigned short* Wt, int K, int N, int nt, int kt, int tid,
               float (*tile)[33])
{
  int n0 = nt<<5, k0 = kt<<5;
  int tx = tid & 31, ty = tid >> 5;
  #pragma unroll
  for (int i=0;i<4;i++)
    tile[ty + i*8][tx] = W[(size_t)(k0 + ty + i*8)*N + n0 + tx];
  __syncthreads();
  #pragma unroll
  for (int i=0;i<4;i++)
    Wt[(size_t)(n0 + ty + i*8)*K + k0 + tx] = f2bf(tile[tx][ty + i*8]);
}

__global__ __launch_bounds__(256) void prep_ln(
    const float* __restrict__ x, const float* __restrict__ xf,
    const float* __restrict__ gx, const float* __restrict__ bx_,
    const float* __restrict__ gt, const float* __restrict__ bt,
    unsigned short* __restrict__ ox, unsigned short* __restrict__ ot,
    const float* __restrict__ Wq, const float* __restrict__ Wk,
    const float* __restrict__ Wv, const float* __restrict__ Wo,
    const float* __restrict__ bk, const float* __restrict__ bv,
    unsigned short* __restrict__ wqt, unsigned short* __restrict__ wkvt,
    unsigned short* __restrict__ wot, float* __restrict__ bkv)
{
  __shared__ float shbuf[1088];   // wtile: 32*33=1056 ; LN: 32
  int blk = blockIdx.x, t = threadIdx.x;
  if (blk >= 10240){
    int id = blk - 10240;
    if (id < 8){
      int i = id*256 + t;
      bkv[i] = (i < 1024) ? bk[i] : bv[i-1024];
      return;
    }
    id -= 8;
    float (*tile)[33] = (float(*)[33])shbuf;
    if (id < 1024){ wtile(Wq, wqt, 1024, 1024, id & 31, id >> 5, t, tile); return; }
    id -= 1024;
    if (id < 768){ wtile(Wk, wkvt, 768, 1024, id & 31, id >> 5, t, tile); return; }
    id -= 768;
    if (id < 768){ wtile(Wv, wkvt + (size_t)1024*768, 768, 1024, id & 31, id >> 5, t, tile); return; }
    id -= 768;
    wtile(Wo, wot, 1024, 1024, id & 31, id >> 5, t, tile);
    return;
  }
  // LN, 4 consecutive rows per block
  const float* src; const float* g; const float* bb; unsigned short* out;
  int D, nvec;
  if (blk < 8192){
    int r0 = blk<<2;
    src = x + (size_t)r0*1024; g = gx; bb = bx_; out = ox + (size_t)r0*1024; D = 1024; nvec = 256;
  } else {
    int r0 = (blk-8192)<<2;
    src = xf + (size_t)r0*768; g = gt; bb = bt; out = ot + (size_t)r0*768; D = 768; nvec = 192;
  }
  float4 v[4];
  float s[4], s2[4];
  #pragma unroll
  for (int r=0;r<4;r++){
    v[r] = make_float4(0.f,0.f,0.f,0.f);
    if (t < nvec) v[r] = ((const float4*)(src + (size_t)r*D))[t];
    s[r]  = v[r].x+v[r].y+v[r].z+v[r].w;
    s2[r] = v[r].x*v[r].x+v[r].y*v[r].y+v[r].z*v[r].z+v[r].w*v[r].w;
  }
  #pragma unroll
  for (int o=32;o;o>>=1){
    #pragma unroll
    for (int r=0;r<4;r++){
      s[r]  += __shfl_down(s[r], o, 64);
      s2[r] += __shfl_down(s2[r], o, 64);
    }
  }
  int w = t>>6;
  if ((t&63)==0){
    #pragma unroll
    for (int r=0;r<4;r++){ shbuf[w*4+r] = s[r]; shbuf[16+w*4+r] = s2[r]; }
  }
  __syncthreads();
  float4 gv = make_float4(0.f,0.f,0.f,0.f), bv4 = make_float4(0.f,0.f,0.f,0.f);
  if (t < nvec){ gv = ((const float4*)g)[t]; bv4 = ((const float4*)bb)[t]; }
  float invD = 1.f/(float)D;
  #pragma unroll
  for (int r=0;r<4;r++){
    float fs  = shbuf[r] + shbuf[4+r] + shbuf[8+r] + shbuf[12+r];
    float fs2 = shbuf[16+r] + shbuf[20+r] + shbuf[24+r] + shbuf[28+r];
    float mean = fs*invD;
    float var  = fmaxf(fs2*invD - mean*mean, 0.f);
    float rstd = rsqrtf(var + 1e-5f);
    if (t < nvec){
      ushort4 o4;
      o4.x = f2bf((v[r].x-mean)*rstd*gv.x + bv4.x);
      o4.y = f2bf((v[r].y-mean)*rstd*gv.y + bv4.y);
      o4.z = f2bf((v[r].z-mean)*rstd*gv.z + bv4.z);
      o4.w = f2bf((v[r].w-mean)*rstd*gv.w + bv4.w);
      *(ushort4*)(out + (size_t)r*D + t*4) = o4;
    }
  }
}

// ---------------- emb GEMM (standalone, k-split) -------------------------------
__global__ __launch_bounds__(256) void embgemm(const float* __restrict__ emb,
    const float* __restrict__ We, float* __restrict__ epart)
{
  __shared__ float a[32][128];
  int cb = blockIdx.x, ks = blockIdx.y, tid = threadIdx.x;
  int k0 = ks<<7;
  #pragma unroll
  for (int it=0; it<4; ++it){
    int fi = it*256 + tid;
    int r = fi>>5, c4 = (fi&31)<<2;
    float4 vv = *(const float4*)(emb + (size_t)r*2048 + k0 + c4);
    vv.x = silu_f(vv.x); vv.y = silu_f(vv.y); vv.z = silu_f(vv.z); vv.w = silu_f(vv.w);
    *(float4*)&a[r][c4] = vv;
  }
  __syncthreads();
  int c0 = (cb<<8) + tid;
  float acc[32];
  #pragma unroll
  for (int r=0;r<32;r++) acc[r]=0.f;
  #pragma unroll 4
  for (int kk=0;kk<128;kk++){
    float wv = We[(size_t)(k0+kk)*2048 + c0];
    #pragma unroll
    for (int r=0;r<32;r++) acc[r] += a[r][kk]*wv;
  }
  #pragma unroll
  for (int r=0;r<32;r++) epart[(size_t)(ks*32 + r)*2048 + c0] = acc[r];
}

// ---------------- GEMM body: round-2 structure (128x128, BK=64, dbuf 64KB) ----
// EPI: 0 = bf16 C. 1 = fp32 C = Xadd + val. 2 = KV fused: N [0,1024) -> K bf16;
//      N [1024,2048) -> V into pre-swizzled vt blocks.
template<int EPI>
DEV void gemm_body(
  const unsigned char* __restrict__ A, const unsigned char* __restrict__ Wt,
  const float* __restrict__ bias, void* __restrict__ Cout,
  const float* __restrict__ Xadd, unsigned char* __restrict__ vt,
  int M, int N, int K, int bx, int by, unsigned char* lds)
{
  const int tid = threadIdx.x, w = tid>>6, lane = tid&63;
  const int l15 = lane&15, lq = lane>>4;
  const int m0 = by<<7, n0 = bx<<7;
  const size_t K2 = (size_t)K<<1;
  const int KT = K>>6;
  const int wr = (w>>1)&1, wc = w&1;
  const int srow = lane>>3;
  const int scb  = (lane&7)<<4;

  f32x4 acc[4][4];
  f32x4 zero = {0.f,0.f,0.f,0.f};
  #pragma unroll
  for (int i=0;i<4;i++)
    #pragma unroll
    for (int j=0;j<4;j++) acc[i][j] = zero;

  auto stage = [&](int buf, int kt){
    unsigned char* ldsA = lds + buf*32768;
    const size_t kb = (size_t)kt<<7;
    #pragma unroll
    for (int inst=0; inst<4; ++inst){
      int base = w*1024 + inst*4096;
      int row  = (base>>7) + srow;
      int cs   = scb ^ ((row&7)<<4);
      gl_lds16(A  + (size_t)(m0+row)*K2 + kb + cs, ldsA + base);
      gl_lds16(Wt + (size_t)(n0+row)*K2 + kb + cs, ldsA + 16384 + base);
    }
  };

  stage(0, 0);
  __syncthreads();
  for (int kt=0; kt<KT; ++kt){
    if (kt+1 < KT) stage((kt+1)&1, kt+1);
    const unsigned char* ldsA = lds + (kt&1)*32768;
    const unsigned char* ldsB = ldsA + 16384;
    bf16x8 af[2][4], bfr[2][4];
    #pragma unroll
    for (int i=0;i<4;i++){
      int r = wr*64 + i*16 + l15;
      int rb = r<<7, sw = (r&7)<<4;
      af[0][i] = *(const bf16x8*)(ldsA + rb + ((lq*16) ^ sw));
      af[1][i] = *(const bf16x8*)(ldsA + rb + ((64 + lq*16) ^ sw));
    }
    #pragma unroll
    for (int j=0;j<4;j++){
      int r = wc*64 + j*16 + l15;
      int rb = r<<7, sw = (r&7)<<4;
      bfr[0][j] = *(const bf16x8*)(ldsB + rb + ((lq*16) ^ sw));
      bfr[1][j] = *(const bf16x8*)(ldsB + rb + ((64 + lq*16) ^ sw));
    }
    #pragma unroll
    for (int kc=0;kc<2;kc++)
      #pragma unroll
      for (int i=0;i<4;i++)
        #pragma unroll
        for (int j=0;j<4;j++)
          acc[i][j] = __builtin_amdgcn_mfma_f32_16x16x32_bf16(af[kc][i], bfr[kc][j], acc[i][j], 0,0,0);
    __syncthreads();
  }
  #pragma unroll
  for (int j=0;j<4;j++){
    int n = n0 + wc*64 + j*16 + l15;
    float bvs = bias[n];
    #pragma unroll
    for (int i=0;i<4;i++){
      int mb = m0 + wr*64 + i*16 + lq*4;
      #pragma unroll
      for (int r=0;r<4;r++){
        int m = mb + r;
        float val = acc[i][j][r] + bvs;
        if (EPI==0){
          ((unsigned short*)Cout)[(size_t)m*N + n] = f2bf(val);
        } else if (EPI==1){
          size_t idx = (size_t)m*N + n;
          ((float*)Cout)[idx] = Xadd[idx] + val;
        } else {
          if (n0 < 1024){
            ((unsigned short*)Cout)[(size_t)m*1024 + n] = f2bf(val);
          } else {
            int d  = (n-1024)&63;
            int hh = (n-1024)>>6;
            int bb_ = m>>8, nk = m&255;
            *(unsigned short*)(vt + ((size_t)(bb_*16+hh)<<15) + d*512
                + (((nk>>3)<<4) ^ ((d&7)<<4)) + ((nk&7)<<1)) = f2bf(val);
          }
        }
      }
    }
  }
}

// ---------------- merged QKV projections (with dead-batch skip) ----------------
// [0,2048): Q-proj (EPI0, batch = by>>3). [2048,3072): KV-proj (EPI2, batch = by>>1).
__global__ __launch_bounds__(256,2) void qkv(
  const unsigned char* __restrict__ xln, const unsigned char* __restrict__ wqt,
  const float* __restrict__ bq, unsigned char* __restrict__ qb,
  const unsigned char* __restrict__ xfn, const unsigned char* __restrict__ wkvt,
  const float* __restrict__ bkv, unsigned char* __restrict__ kb,
  unsigned char* __restrict__ vtb, const int* __restrict__ cond)
{
  __shared__ __align__(16) unsigned char lds[65536];
  int wg = blockIdx.x;
  if (wg < 2048){
    int lg = (wg & 7) * 256 + (wg >> 3);
    int by = lg >> 3;
    if (cond[by >> 3] % 10 == 0) return;   // dead batch: q never read
    gemm_body<0>(xln, wqt, bq, qb, nullptr, nullptr, 32768, 1024, 1024, lg & 7, by, lds);
  } else {
    int w2 = wg - 2048;
    int lg = (w2 & 7) * 128 + (w2 >> 3);
    int by = lg >> 4;
    if (cond[by >> 1] % 10 == 0) return;   // dead batch: k/v never read
    gemm_body<2>(xfn, wkvt, bkv, kb, nullptr, vtb, 8192, 2048, 768, lg & 15, by, lds);
  }
}

// ---------------- fused cross-attention + embred tail --------------------------
// [0,8192): attention blocks. [8192,8224): embred (eo = sum epart + be).
__global__ __launch_bounds__(256,2) void attn64(
  const unsigned char* __restrict__ qg, const unsigned char* __restrict__ kg,
  int kstride, const unsigned char* __restrict__ vtg, const int* __restrict__ cond,
  unsigned short* __restrict__ yout,
  const float* __restrict__ epart, const float* __restrict__ be,
  float* __restrict__ eo)
{
  __shared__ __align__(16) unsigned char lds[73728];
  const int wg = blockIdx.x;
  const int tid = threadIdx.x;
  if (wg >= 8192){
    int idx0 = (wg - 8192) * 2048 + tid;
    #pragma unroll
    for (int e=0;e<8;e++){
      int idx = idx0 + e*256;
      float s = be[idx & 2047];
      #pragma unroll
      for (int ks=0;ks<16;ks++) s += epart[(size_t)ks*65536 + idx];
      eo[idx] = s;
    }
    return;
  }
  const int lg = (wg & 7) * 1024 + (wg >> 3);
  const int t0 = (lg & 15) * 64;
  const int h  = (lg >> 4) & 15;
  const int b  = lg >> 8;
  const int w = tid>>6, lane = tid&63;
  const int l15 = lane&15, lq = lane>>4;

  if (cond[b] % 10 == 0){
    int row = t0 + (tid>>2);
    unsigned short* dst = yout + (size_t)(b*1024 + row)*1024 + h*64 + (tid&3)*16;
    u16x8 z = {0,0,0,0,0,0,0,0};
    *(u16x8*)dst = z;
    *(u16x8*)(dst + 8) = z;
    return;
  }

  const unsigned char* kbase = kg + (size_t)b*256*kstride + (size_t)h*128;
  const unsigned char* vtb   = vtg + (size_t)(b*16+h)*32768;
  #pragma unroll
  for (int i=0;i<8;i++){
    int base = (w*8+i)*1024;
    int n  = (base>>7) + (lane>>3);
    int cb = (lane&7)<<4;
    gl_lds16(kbase + (size_t)n*kstride + (cb ^ ((n&7)<<4)), lds + base);
    gl_lds16(vtb + base + lane*16, lds + 32768 + base);
  }
  const unsigned char* qbase = qg + (size_t)(b*1024 + t0)*2048 + h*128;
  #pragma unroll
  for (int i=0;i<2;i++){
    int row = i*32 + (tid>>3);
    int cs  = ((tid&7)<<4) ^ ((row&7)<<4);
    gl_lds16(qbase + (size_t)row*2048 + cs, lds + 65536 + i*4096 + w*1024);
  }
  __syncthreads();

  const int qr = w*16 + l15;
  const int qsw = (qr&7)<<4;
  bf16x8 aq0 = *(const bf16x8*)(lds + 65536 + qr*128 + ((lq*16) ^ qsw));
  bf16x8 aq1 = *(const bf16x8*)(lds + 65536 + qr*128 + ((64 + lq*16) ^ qsw));

  f32x4 zero = {0.f,0.f,0.f,0.f};
  f32x4 s[16];
  #pragma unroll
  for (int nt=0;nt<16;nt++) s[nt] = zero;
  #pragma unroll
  for (int nt=0;nt<16;nt++){
    int n = nt*16 + l15;
    int rb = n<<7, sw = (n&7)<<4;
    bf16x8 kb0 = *(const bf16x8*)(lds + rb + ((lq*16) ^ sw));
    bf16x8 kb1 = *(const bf16x8*)(lds + rb + ((64 + lq*16) ^ sw));
    s[nt] = __builtin_amdgcn_mfma_f32_16x16x32_bf16(aq0, kb0, s[nt], 0,0,0);
    s[nt] = __builtin_amdgcn_mfma_f32_16x16x32_bf16(aq1, kb1, s[nt], 0,0,0);
  }
  #pragma unroll
  for (int r=0;r<4;r++){
    float m = s[0][r];
    #pragma unroll
    for (int nt=1;nt<16;nt++) m = fmaxf(m, s[nt][r]);
    m = fmaxf(m, __shfl_xor(m,1,64));
    m = fmaxf(m, __shfl_xor(m,2,64));
    m = fmaxf(m, __shfl_xor(m,4,64));
    m = fmaxf(m, __shfl_xor(m,8,64));
    float sum = 0.f;
    #pragma unroll
    for (int nt=0;nt<16;nt++){ float p = __expf(s[nt][r]-m); s[nt][r]=p; sum+=p; }
    sum += __shfl_xor(sum,1,64);
    sum += __shfl_xor(sum,2,64);
    sum += __shfl_xor(sum,4,64);
    sum += __shfl_xor(sum,8,64);
    float inv = 1.f/sum;
    #pragma unroll
    for (int nt=0;nt<16;nt++) s[nt][r] *= inv;
  }
  __syncthreads();
  #pragma unroll
  for (int nt=0;nt<16;nt++){
    int n = nt*16 + l15;
    int nb = (n>>3)<<4, nr = (n&7)<<1;
    #pragma unroll
    for (int r=0;r<4;r++){
      int tl = w*16 + lq*4 + r;
      *(unsigned short*)(lds + tl*512 + ((nb ^ ((tl&7)<<4)) | nr)) = f2bf(s[nt][r]);
    }
  }
  __syncthreads();
  f32x4 yv[4];
  #pragma unroll
  for (int dt=0;dt<4;dt++) yv[dt] = zero;
  const int tl = w*16 + l15;
  const int swp = (tl&7)<<4;
  #pragma unroll
  for (int kc=0;kc<8;kc++){
    bf16x8 pa = *(const bf16x8*)(lds + tl*512 + ((kc*64 + lq*16) ^ swp));
    #pragma unroll
    for (int dt=0;dt<4;dt++){
      int d = dt*16 + l15;
      bf16x8 vbv = *(const bf16x8*)(lds + 32768 + d*512 + ((kc*64 + lq*16) ^ ((d&7)<<4)));
      yv[dt] = __builtin_amdgcn_mfma_f32_16x16x32_bf16(pa, vbv, yv[dt], 0,0,0);
    }
  }
  #pragma unroll
  for (int dt=0;dt<4;dt++){
    #pragma unroll
    for (int r=0;r<4;r++){
      int tt = t0 + w*16 + lq*4 + r;
      yout[(size_t)(b*1024 + tt)*1024 + h*64 + dt*16 + l15] = f2bf(yv[dt][r]);
    }
  }
}

// ---------------- stylization --------------------------------------------------
__global__ __launch_bounds__(256) void styl(const unsigned short* __restrict__ y,
    const float* __restrict__ g, const float* __restrict__ bt,
    const float* __restrict__ eo, unsigned short* __restrict__ hout)
{
  int row = blockIdx.x, t = threadIdx.x, b = row>>10;
  ushort4 yv4 = ((const ushort4*)(y + (size_t)row*1024))[t];
  float in[4] = {bf2f(yv4.x), bf2f(yv4.y), bf2f(yv4.z), bf2f(yv4.w)};
  float s  = in[0]+in[1]+in[2]+in[3];
  float s2 = in[0]*in[0]+in[1]*in[1]+in[2]*in[2]+in[3]*in[3];
  #pragma unroll
  for (int o=32;o;o>>=1){ s += __shfl_down(s,o,64); s2 += __shfl_down(s2,o,64); }
  __shared__ float red[8];
  if ((t&63)==0){ red[t>>6]=s; red[4+(t>>6)]=s2; }
  __syncthreads();
  float fs  = red[0]+red[1]+red[2]+red[3];
  float fs2 = red[4]+red[5]+red[6]+red[7];
  float mean = fs*(1.f/1024.f);
  float var  = fmaxf(fs2*(1.f/1024.f) - mean*mean, 0.f);
  float rstd = rsqrtf(var + 1e-5f);
  float4 gv = ((const float4*)g)[t];
  float4 bv = ((const float4*)bt)[t];
  float4 sc = ((const float4*)(eo + (size_t)b*2048))[t];
  float4 sh = ((const float4*)(eo + (size_t)b*2048 + 1024))[t];
  float gg[4]  = {gv.x,gv.y,gv.z,gv.w};
  float bb[4]  = {bv.x,bv.y,bv.z,bv.w};
  float scs[4] = {sc.x,sc.y,sc.z,sc.w};
  float shs[4] = {sh.x,sh.y,sh.z,sh.w};
  unsigned short oo[4];
  #pragma unroll
  for (int c=0;c<4;c++){
    float hv = (in[c]-mean)*rstd*gg[c] + bb[c];
    hv = hv*(1.f+scs[c]) + shs[c];
    oo[c] = f2bf(silu_f(hv));
  }
  ushort4 o4; o4.x=oo[0]; o4.y=oo[1]; o4.z=oo[2]; o4.w=oo[3];
  *(ushort4*)(hout + (size_t)row*1024 + t*4) = o4;
}

// ---------------- O-projection + residual --------------------------------------
__global__ __launch_bounds__(256,2) void gemmO(
  const unsigned char* __restrict__ A, const unsigned char* __restrict__ Wt,
  const float* __restrict__ bias, float* __restrict__ Cout,
  const float* __restrict__ Xadd)
{
  __shared__ __align__(16) unsigned char lds[65536];
  int wg = blockIdx.x;
  int lg = (wg & 7) * 256 + (wg >> 3);
  gemm_body<1>(A, Wt, bias, Cout, Xadd, nullptr, 32768, 1024, 1024, lg & 7, lg >> 3, lds);
}

// ---------------- launcher ----------------------------------------------------
extern "C" void kernel_launch(void* const* d_in, const int* in_sizes, int n_in,
                              void* d_out, int out_size, void* d_ws, size_t ws_size,
                              hipStream_t stream) {
  const float* x      = (const float*)d_in[0];
  const float* xf     = (const float*)d_in[1];
  const float* emb    = (const float*)d_in[2];
  const int*   cond   = (const int*)d_in[4];
  const float* ln_x_g = (const float*)d_in[5];
  const float* ln_x_b = (const float*)d_in[6];
  const float* ln_t_g = (const float*)d_in[7];
  const float* ln_t_b = (const float*)d_in[8];
  const float* Wq     = (const float*)d_in[9];
  const float* bq     = (const float*)d_in[10];
  const float* Wk     = (const float*)d_in[11];
  const float* bk     = (const float*)d_in[12];
  const float* Wv     = (const float*)d_in[13];
  const float* bv     = (const float*)d_in[14];
  const float* We     = (const float*)d_in[15];
  const float* be     = (const float*)d_in[16];
  const float* ln_y_g = (const float*)d_in[17];
  const float* ln_y_b = (const float*)d_in[18];
  const float* Wo     = (const float*)d_in[19];
  const float* bo     = (const float*)d_in[20];
  float* out = (float*)d_out;

  unsigned char* ws = (unsigned char*)d_ws;
  size_t off = 0;
  auto take = [&](size_t n){ unsigned char* p = ws + off; off += (n + 255) & ~(size_t)255; return p; };
  unsigned char* r1    = take(67108864);   // xln bf16 -> h bf16
  unsigned char* qb    = take(67108864);   // q bf16 -> y bf16 (in place)
  unsigned char* xfn   = take(12582912);   // LN(xf) bf16
  unsigned char* kb    = take(16777216);   // k bf16 [8192][1024]
  unsigned char* vtb   = take(16777216);   // v^T pre-swizzled bf16
  unsigned char* wqt   = take(2097152);
  unsigned char* wkvt  = take(3145728);
  unsigned char* wot   = take(2097152);
  unsigned char* eo    = take(262144);
  unsigned char* bkv   = take(8192);
  unsigned char* epart = take(4194304);    // [16][32][2048] fp32

  dim3 blk(256);
  // 1) LN (4 rows/block) + weight prep   [56 VGPR — embgemm kept OUT on purpose]
  prep_ln<<<13832, blk, 0, stream>>>(x, xf, ln_x_g, ln_x_b, ln_t_g, ln_t_b,
      (unsigned short*)r1, (unsigned short*)xfn,
      Wq, Wk, Wv, Wo, bk, bv,
      (unsigned short*)wqt, (unsigned short*)wkvt, (unsigned short*)wot, (float*)bkv);
  // 2) emb GEMM (standalone)
  embgemm<<<dim3(8,16), blk, 0, stream>>>(emb, We, (float*)epart);
  // 3) Q-proj + KV-proj (fused V->vt), dead-batch skip, exactly 6 occupancy-waves
  qkv<<<3072, blk, 0, stream>>>(r1, wqt, bq, qb,
      xfn, wkvt, (const float*)bkv, kb, vtb, cond);
  // 4) attention (y bf16 in place over q) + embred tail
  attn64<<<8224, blk, 0, stream>>>(qb, kb, 2048, vtb, cond, (unsigned short*)qb,
      (const float*)epart, be, (float*)eo);
  // 5) stylization -> h bf16 (overwrites r1)
  styl<<<32768, blk, 0, stream>>>((const unsigned short*)qb, ln_y_g, ln_y_b, (const float*)eo, (unsigned short*)r1);
  // 6) O-projection + residual
  gemmO<<<2048, blk, 0, stream>>>(r1, wot, bo, out, x);
}

// Round 12
// 399.794 us; speedup vs baseline: 1.1686x; 1.0956x over previous
//
#include <hip/hip_runtime.h>
#include <hip/hip_bf16.h>

#define DEV __device__ __forceinline__

typedef __attribute__((ext_vector_type(8))) short bf16x8;
typedef __attribute__((ext_vector_type(4))) float f32x4;
typedef __attribute__((ext_vector_type(8))) unsigned short u16x8;

DEV unsigned short f2bf(float f){
  unsigned int b = __float_as_uint(f);
  return (unsigned short)((b + 0x7fffu + ((b >> 16) & 1u)) >> 16);
}
DEV float bf2f(unsigned short u){ return __uint_as_float(((unsigned int)u)<<16); }

DEV float silu_f(float v){ return v / (1.f + __expf(-v)); }

DEV void gl_lds16(const void* g, void* l){
  __builtin_amdgcn_global_load_lds((const __attribute__((address_space(1))) void*)g,
                                   (__attribute__((address_space(3))) void*)l, 16, 0, 0);
}

// ---------- prep_ln: LN (4 rows/blk, dead-batch skip) + weight prep + bias ----
// [0,8192): x-LN ; [8192,10240): xf-LN ; [10240,10248): bias concat ;
// [10248,13832): weight tiles (3584).
// NOTE: embgemm kept OUT of this kernel (R10: its footprint raises VGPR 56->88
// and cuts LN occupancy 26->16%). It lives in qkv's grid tail instead, where
// the host kernel already has a larger footprint.
DEV void wtile(const float* W, unsigned short* Wt, int K, int N, int nt, int kt, int tid,
               float (*tile)[33])
{
  int n0 = nt<<5, k0 = kt<<5;
  int tx = tid & 31, ty = tid >> 5;
  #pragma unroll
  for (int i=0;i<4;i++)
    tile[ty + i*8][tx] = W[(size_t)(k0 + ty + i*8)*N + n0 + tx];
  __syncthreads();
  #pragma unroll
  for (int i=0;i<4;i++)
    Wt[(size_t)(n0 + ty + i*8)*K + k0 + tx] = f2bf(tile[tx][ty + i*8]);
}

__global__ __launch_bounds__(256) void prep_ln(
    const float* __restrict__ x, const float* __restrict__ xf,
    const float* __restrict__ gx, const float* __restrict__ bx_,
    const float* __restrict__ gt, const float* __restrict__ bt,
    unsigned short* __restrict__ ox, unsigned short* __restrict__ ot,
    const float* __restrict__ Wq, const float* __restrict__ Wk,
    const float* __restrict__ Wv, const float* __restrict__ Wo,
    const float* __restrict__ bk, const float* __restrict__ bv,
    unsigned short* __restrict__ wqt, unsigned short* __restrict__ wkvt,
    unsigned short* __restrict__ wot, float* __restrict__ bkv,
    const int* __restrict__ cond)
{
  __shared__ float shbuf[1088];   // wtile: 32*33=1056 ; LN: 32
  int blk = blockIdx.x, t = threadIdx.x;
  if (blk >= 10240){
    int id = blk - 10240;
    if (id < 8){
      int i = id*256 + t;
      bkv[i] = (i < 1024) ? bk[i] : bv[i-1024];
      return;
    }
    id -= 8;
    float (*tile)[33] = (float(*)[33])shbuf;
    if (id < 1024){ wtile(Wq, wqt, 1024, 1024, id & 31, id >> 5, t, tile); return; }
    id -= 1024;
    if (id < 768){ wtile(Wk, wkvt, 768, 1024, id & 31, id >> 5, t, tile); return; }
    id -= 768;
    if (id < 768){ wtile(Wv, wkvt + (size_t)1024*768, 768, 1024, id & 31, id >> 5, t, tile); return; }
    id -= 768;
    wtile(Wo, wot, 1024, 1024, id & 31, id >> 5, t, tile);
    return;
  }
  // LN, 4 consecutive rows per block; skip rows of dead batches (never read:
  // their Q/KV-GEMM blocks and attention blocks all early-out).
  const float* src; const float* g; const float* bb; unsigned short* out;
  int D, nvec;
  if (blk < 8192){
    if (cond[blk >> 8] % 10 == 0) return;          // 256 blocks per batch
    int r0 = blk<<2;
    src = x + (size_t)r0*1024; g = gx; bb = bx_; out = ox + (size_t)r0*1024; D = 1024; nvec = 256;
  } else {
    if (cond[(blk - 8192) >> 6] % 10 == 0) return; // 64 blocks per batch
    int r0 = (blk-8192)<<2;
    src = xf + (size_t)r0*768; g = gt; bb = bt; out = ot + (size_t)r0*768; D = 768; nvec = 192;
  }
  float4 v[4];
  float s[4], s2[4];
  #pragma unroll
  for (int r=0;r<4;r++){
    v[r] = make_float4(0.f,0.f,0.f,0.f);
    if (t < nvec) v[r] = ((const float4*)(src + (size_t)r*D))[t];
    s[r]  = v[r].x+v[r].y+v[r].z+v[r].w;
    s2[r] = v[r].x*v[r].x+v[r].y*v[r].y+v[r].z*v[r].z+v[r].w*v[r].w;
  }
  #pragma unroll
  for (int o=32;o;o>>=1){
    #pragma unroll
    for (int r=0;r<4;r++){
      s[r]  += __shfl_down(s[r], o, 64);
      s2[r] += __shfl_down(s2[r], o, 64);
    }
  }
  int w = t>>6;
  if ((t&63)==0){
    #pragma unroll
    for (int r=0;r<4;r++){ shbuf[w*4+r] = s[r]; shbuf[16+w*4+r] = s2[r]; }
  }
  __syncthreads();
  float4 gv = make_float4(0.f,0.f,0.f,0.f), bv4 = make_float4(0.f,0.f,0.f,0.f);
  if (t < nvec){ gv = ((const float4*)g)[t]; bv4 = ((const float4*)bb)[t]; }
  float invD = 1.f/(float)D;
  #pragma unroll
  for (int r=0;r<4;r++){
    float fs  = shbuf[r] + shbuf[4+r] + shbuf[8+r] + shbuf[12+r];
    float fs2 = shbuf[16+r] + shbuf[20+r] + shbuf[24+r] + shbuf[28+r];
    float mean = fs*invD;
    float var  = fmaxf(fs2*invD - mean*mean, 0.f);
    float rstd = rsqrtf(var + 1e-5f);
    if (t < nvec){
      ushort4 o4;
      o4.x = f2bf((v[r].x-mean)*rstd*gv.x + bv4.x);
      o4.y = f2bf((v[r].y-mean)*rstd*gv.y + bv4.y);
      o4.z = f2bf((v[r].z-mean)*rstd*gv.z + bv4.z);
      o4.w = f2bf((v[r].w-mean)*rstd*gv.w + bv4.w);
      *(ushort4*)(out + (size_t)r*D + t*4) = o4;
    }
  }
}

// ---------------- GEMM body: round-2 structure (128x128, BK=64, dbuf 64KB) ----
// EPI: 0 = bf16 C. 1 = fp32 C = Xadd + val. 2 = KV fused: N [0,1024) -> K bf16;
//      N [1024,2048) -> V into pre-swizzled vt blocks.
template<int EPI>
DEV void gemm_body(
  const unsigned char* __restrict__ A, const unsigned char* __restrict__ Wt,
  const float* __restrict__ bias, void* __restrict__ Cout,
  const float* __restrict__ Xadd, unsigned char* __restrict__ vt,
  int M, int N, int K, int bx, int by, unsigned char* lds)
{
  const int tid = threadIdx.x, w = tid>>6, lane = tid&63;
  const int l15 = lane&15, lq = lane>>4;
  const int m0 = by<<7, n0 = bx<<7;
  const size_t K2 = (size_t)K<<1;
  const int KT = K>>6;
  const int wr = (w>>1)&1, wc = w&1;
  const int srow = lane>>3;
  const int scb  = (lane&7)<<4;

  f32x4 acc[4][4];
  f32x4 zero = {0.f,0.f,0.f,0.f};
  #pragma unroll
  for (int i=0;i<4;i++)
    #pragma unroll
    for (int j=0;j<4;j++) acc[i][j] = zero;

  auto stage = [&](int buf, int kt){
    unsigned char* ldsA = lds + buf*32768;
    const size_t kb = (size_t)kt<<7;
    #pragma unroll
    for (int inst=0; inst<4; ++inst){
      int base = w*1024 + inst*4096;
      int row  = (base>>7) + srow;
      int cs   = scb ^ ((row&7)<<4);
      gl_lds16(A  + (size_t)(m0+row)*K2 + kb + cs, ldsA + base);
      gl_lds16(Wt + (size_t)(n0+row)*K2 + kb + cs, ldsA + 16384 + base);
    }
  };

  stage(0, 0);
  __syncthreads();
  for (int kt=0; kt<KT; ++kt){
    if (kt+1 < KT) stage((kt+1)&1, kt+1);
    const unsigned char* ldsA = lds + (kt&1)*32768;
    const unsigned char* ldsB = ldsA + 16384;
    bf16x8 af[2][4], bfr[2][4];
    #pragma unroll
    for (int i=0;i<4;i++){
      int r = wr*64 + i*16 + l15;
      int rb = r<<7, sw = (r&7)<<4;
      af[0][i] = *(const bf16x8*)(ldsA + rb + ((lq*16) ^ sw));
      af[1][i] = *(const bf16x8*)(ldsA + rb + ((64 + lq*16) ^ sw));
    }
    #pragma unroll
    for (int j=0;j<4;j++){
      int r = wc*64 + j*16 + l15;
      int rb = r<<7, sw = (r&7)<<4;
      bfr[0][j] = *(const bf16x8*)(ldsB + rb + ((lq*16) ^ sw));
      bfr[1][j] = *(const bf16x8*)(ldsB + rb + ((64 + lq*16) ^ sw));
    }
    #pragma unroll
    for (int kc=0;kc<2;kc++)
      #pragma unroll
      for (int i=0;i<4;i++)
        #pragma unroll
        for (int j=0;j<4;j++)
          acc[i][j] = __builtin_amdgcn_mfma_f32_16x16x32_bf16(af[kc][i], bfr[kc][j], acc[i][j], 0,0,0);
    __syncthreads();
  }
  #pragma unroll
  for (int j=0;j<4;j++){
    int n = n0 + wc*64 + j*16 + l15;
    float bvs = bias[n];
    #pragma unroll
    for (int i=0;i<4;i++){
      int mb = m0 + wr*64 + i*16 + lq*4;
      #pragma unroll
      for (int r=0;r<4;r++){
        int m = mb + r;
        float val = acc[i][j][r] + bvs;
        if (EPI==0){
          ((unsigned short*)Cout)[(size_t)m*N + n] = f2bf(val);
        } else if (EPI==1){
          size_t idx = (size_t)m*N + n;
          ((float*)Cout)[idx] = Xadd[idx] + val;
        } else {
          if (n0 < 1024){
            ((unsigned short*)Cout)[(size_t)m*1024 + n] = f2bf(val);
          } else {
            int d  = (n-1024)&63;
            int hh = (n-1024)>>6;
            int bb_ = m>>8, nk = m&255;
            *(unsigned short*)(vt + ((size_t)(bb_*16+hh)<<15) + d*512
                + (((nk>>3)<<4) ^ ((d&7)<<4)) + ((nk&7)<<1)) = f2bf(val);
          }
        }
      }
    }
  }
}

// ---------------- merged QKV projections + embgemm tail ------------------------
// [0,2048): Q-proj (EPI0, batch = by>>3, dead-batch skip).
// [2048,3072): KV-proj (EPI2, batch = by>>1, dead-batch skip).
// [3072,3200): embgemm k-split (cb = id&7, ks = id>>3) -> epart.
// embgemm guest fits inside host footprint (<=88 VGPR, 16KB of the 64KB LDS),
// so host occupancy is unchanged (R10 lesson). Consumer (embred) is in attn64.
__global__ __launch_bounds__(256,2) void qkv(
  const unsigned char* __restrict__ xln, const unsigned short* __restrict__ wqt,
  const float* __restrict__ bq, unsigned char* __restrict__ qb,
  const unsigned char* __restrict__ xfn, const unsigned short* __restrict__ wkvt,
  const float* __restrict__ bkv, unsigned char* __restrict__ kb,
  unsigned char* __restrict__ vtb, const int* __restrict__ cond,
  const float* __restrict__ emb, const float* __restrict__ We,
  float* __restrict__ epart)
{
  __shared__ __align__(16) unsigned char lds[65536];
  int wg = blockIdx.x;
  if (wg < 2048){
    int lg = (wg & 7) * 256 + (wg >> 3);
    int by = lg >> 3;
    if (cond[by >> 3] % 10 == 0) return;   // dead batch: q never read
    gemm_body<0>(xln, (const unsigned char*)wqt, bq, qb, nullptr, nullptr,
                 32768, 1024, 1024, lg & 7, by, lds);
  } else if (wg < 3072){
    int w2 = wg - 2048;
    int lg = (w2 & 7) * 128 + (w2 >> 3);
    int by = lg >> 4;
    if (cond[by >> 1] % 10 == 0) return;   // dead batch: k/v never read
    gemm_body<2>(xfn, (const unsigned char*)wkvt, bkv, kb, nullptr, vtb,
                 8192, 2048, 768, lg & 15, by, lds);
  } else {
    // embgemm: silu(emb)[32][2048] @ We k-slice -> epart
    int id = wg - 3072, t = threadIdx.x;
    float (*a)[128] = (float(*)[128])lds;
    int cb = id & 7, ks = id >> 3;
    int k0 = ks << 7;
    #pragma unroll
    for (int it=0; it<4; ++it){
      int fi = it*256 + t;
      int r = fi>>5, c4 = (fi&31)<<2;
      float4 vv = *(const float4*)(emb + (size_t)r*2048 + k0 + c4);
      vv.x = silu_f(vv.x); vv.y = silu_f(vv.y); vv.z = silu_f(vv.z); vv.w = silu_f(vv.w);
      *(float4*)&a[r][c4] = vv;
    }
    __syncthreads();
    int c0 = (cb<<8) + t;
    float accv[32];
    #pragma unroll
    for (int r=0;r<32;r++) accv[r]=0.f;
    #pragma unroll 4
    for (int kk=0;kk<128;kk++){
      float wv = We[(size_t)(k0+kk)*2048 + c0];
      #pragma unroll
      for (int r=0;r<32;r++) accv[r] += a[r][kk]*wv;
    }
    #pragma unroll
    for (int r=0;r<32;r++) epart[(size_t)(ks*32 + r)*2048 + c0] = accv[r];
  }
}

// ---------------- fused cross-attention + embred tail --------------------------
// [0,8192): attention blocks. [8192,8224): embred (eo = sum epart + be).
__global__ __launch_bounds__(256,2) void attn64(
  const unsigned char* __restrict__ qg, const unsigned char* __restrict__ kg,
  int kstride, const unsigned char* __restrict__ vtg, const int* __restrict__ cond,
  unsigned short* __restrict__ yout,
  const float* __restrict__ epart, const float* __restrict__ be,
  float* __restrict__ eo)
{
  __shared__ __align__(16) unsigned char lds[73728];
  const int wg = blockIdx.x;
  const int tid = threadIdx.x;
  if (wg >= 8192){
    int idx0 = (wg - 8192) * 2048 + tid;
    #pragma unroll
    for (int e=0;e<8;e++){
      int idx = idx0 + e*256;
      float s = be[idx & 2047];
      #pragma unroll
      for (int ks=0;ks<16;ks++) s += epart[(size_t)ks*65536 + idx];
      eo[idx] = s;
    }
    return;
  }
  const int lg = (wg & 7) * 1024 + (wg >> 3);
  const int t0 = (lg & 15) * 64;
  const int h  = (lg >> 4) & 15;
  const int b  = lg >> 8;
  const int w = tid>>6, lane = tid&63;
  const int l15 = lane&15, lq = lane>>4;

  if (cond[b] % 10 == 0){
    int row = t0 + (tid>>2);
    unsigned short* dst = yout + (size_t)(b*1024 + row)*1024 + h*64 + (tid&3)*16;
    u16x8 z = {0,0,0,0,0,0,0,0};
    *(u16x8*)dst = z;
    *(u16x8*)(dst + 8) = z;
    return;
  }

  const unsigned char* kbase = kg + (size_t)b*256*kstride + (size_t)h*128;
  const unsigned char* vtb   = vtg + (size_t)(b*16+h)*32768;
  #pragma unroll
  for (int i=0;i<8;i++){
    int base = (w*8+i)*1024;
    int n  = (base>>7) + (lane>>3);
    int cb = (lane&7)<<4;
    gl_lds16(kbase + (size_t)n*kstride + (cb ^ ((n&7)<<4)), lds + base);
    gl_lds16(vtb + base + lane*16, lds + 32768 + base);
  }
  const unsigned char* qbase = qg + (size_t)(b*1024 + t0)*2048 + h*128;
  #pragma unroll
  for (int i=0;i<2;i++){
    int row = i*32 + (tid>>3);
    int cs  = ((tid&7)<<4) ^ ((row&7)<<4);
    gl_lds16(qbase + (size_t)row*2048 + cs, lds + 65536 + i*4096 + w*1024);
  }
  __syncthreads();

  const int qr = w*16 + l15;
  const int qsw = (qr&7)<<4;
  bf16x8 aq0 = *(const bf16x8*)(lds + 65536 + qr*128 + ((lq*16) ^ qsw));
  bf16x8 aq1 = *(const bf16x8*)(lds + 65536 + qr*128 + ((64 + lq*16) ^ qsw));

  f32x4 zero = {0.f,0.f,0.f,0.f};
  f32x4 s[16];
  #pragma unroll
  for (int nt=0;nt<16;nt++) s[nt] = zero;
  #pragma unroll
  for (int nt=0;nt<16;nt++){
    int n = nt*16 + l15;
    int rb = n<<7, sw = (n&7)<<4;
    bf16x8 kb0 = *(const bf16x8*)(lds + rb + ((lq*16) ^ sw));
    bf16x8 kb1 = *(const bf16x8*)(lds + rb + ((64 + lq*16) ^ sw));
    s[nt] = __builtin_amdgcn_mfma_f32_16x16x32_bf16(aq0, kb0, s[nt], 0,0,0);
    s[nt] = __builtin_amdgcn_mfma_f32_16x16x32_bf16(aq1, kb1, s[nt], 0,0,0);
  }
  #pragma unroll
  for (int r=0;r<4;r++){
    float m = s[0][r];
    #pragma unroll
    for (int nt=1;nt<16;nt++) m = fmaxf(m, s[nt][r]);
    m = fmaxf(m, __shfl_xor(m,1,64));
    m = fmaxf(m, __shfl_xor(m,2,64));
    m = fmaxf(m, __shfl_xor(m,4,64));
    m = fmaxf(m, __shfl_xor(m,8,64));
    float sum = 0.f;
    #pragma unroll
    for (int nt=0;nt<16;nt++){ float p = __expf(s[nt][r]-m); s[nt][r]=p; sum+=p; }
    sum += __shfl_xor(sum,1,64);
    sum += __shfl_xor(sum,2,64);
    sum += __shfl_xor(sum,4,64);
    sum += __shfl_xor(sum,8,64);
    float inv = 1.f/sum;
    #pragma unroll
    for (int nt=0;nt<16;nt++) s[nt][r] *= inv;
  }
  __syncthreads();
  #pragma unroll
  for (int nt=0;nt<16;nt++){
    int n = nt*16 + l15;
    int nb = (n>>3)<<4, nr = (n&7)<<1;
    #pragma unroll
    for (int r=0;r<4;r++){
      int tl = w*16 + lq*4 + r;
      *(unsigned short*)(lds + tl*512 + ((nb ^ ((tl&7)<<4)) | nr)) = f2bf(s[nt][r]);
    }
  }
  __syncthreads();
  f32x4 yv[4];
  #pragma unroll
  for (int dt=0;dt<4;dt++) yv[dt] = zero;
  const int tl = w*16 + l15;
  const int swp = (tl&7)<<4;
  #pragma unroll
  for (int kc=0;kc<8;kc++){
    bf16x8 pa = *(const bf16x8*)(lds + tl*512 + ((kc*64 + lq*16) ^ swp));
    #pragma unroll
    for (int dt=0;dt<4;dt++){
      int d = dt*16 + l15;
      bf16x8 vbv = *(const bf16x8*)(lds + 32768 + d*512 + ((kc*64 + lq*16) ^ ((d&7)<<4)));
      yv[dt] = __builtin_amdgcn_mfma_f32_16x16x32_bf16(pa, vbv, yv[dt], 0,0,0);
    }
  }
  #pragma unroll
  for (int dt=0;dt<4;dt++){
    #pragma unroll
    for (int r=0;r<4;r++){
      int tt = t0 + w*16 + lq*4 + r;
      yout[(size_t)(b*1024 + tt)*1024 + h*64 + dt*16 + l15] = f2bf(yv[dt][r]);
    }
  }
}

// ---------------- stylization --------------------------------------------------
__global__ __launch_bounds__(256) void styl(const unsigned short* __restrict__ y,
    const float* __restrict__ g, const float* __restrict__ bt,
    const float* __restrict__ eo, unsigned short* __restrict__ hout)
{
  int row = blockIdx.x, t = threadIdx.x, b = row>>10;
  ushort4 yv4 = ((const ushort4*)(y + (size_t)row*1024))[t];
  float in[4] = {bf2f(yv4.x), bf2f(yv4.y), bf2f(yv4.z), bf2f(yv4.w)};
  float s  = in[0]+in[1]+in[2]+in[3];
  float s2 = in[0]*in[0]+in[1]*in[1]+in[2]*in[2]+in[3]*in[3];
  #pragma unroll
  for (int o=32;o;o>>=1){ s += __shfl_down(s,o,64); s2 += __shfl_down(s2,o,64); }
  __shared__ float red[8];
  if ((t&63)==0){ red[t>>6]=s; red[4+(t>>6)]=s2; }
  __syncthreads();
  float fs  = red[0]+red[1]+red[2]+red[3];
  float fs2 = red[4]+red[5]+red[6]+red[7];
  float mean = fs*(1.f/1024.f);
  float var  = fmaxf(fs2*(1.f/1024.f) - mean*mean, 0.f);
  float rstd = rsqrtf(var + 1e-5f);
  float4 gv = ((const float4*)g)[t];
  float4 bv = ((const float4*)bt)[t];
  float4 sc = ((const float4*)(eo + (size_t)b*2048))[t];
  float4 sh = ((const float4*)(eo + (size_t)b*2048 + 1024))[t];
  float gg[4]  = {gv.x,gv.y,gv.z,gv.w};
  float bb[4]  = {bv.x,bv.y,bv.z,bv.w};
  float scs[4] = {sc.x,sc.y,sc.z,sc.w};
  float shs[4] = {sh.x,sh.y,sh.z,sh.w};
  unsigned short oo[4];
  #pragma unroll
  for (int c=0;c<4;c++){
    float hv = (in[c]-mean)*rstd*gg[c] + bb[c];
    hv = hv*(1.f+scs[c]) + shs[c];
    oo[c] = f2bf(silu_f(hv));
  }
  ushort4 o4; o4.x=oo[0]; o4.y=oo[1]; o4.z=oo[2]; o4.w=oo[3];
  *(ushort4*)(hout + (size_t)row*1024 + t*4) = o4;
}

// ---------------- O-projection + residual --------------------------------------
__global__ __launch_bounds__(256,2) void gemmO(
  const unsigned char* __restrict__ A, const unsigned char* __restrict__ Wt,
  const float* __restrict__ bias, float* __restrict__ Cout,
  const float* __restrict__ Xadd)
{
  __shared__ __align__(16) unsigned char lds[65536];
  int wg = blockIdx.x;
  int lg = (wg & 7) * 256 + (wg >> 3);
  gemm_body<1>(A, Wt, bias, Cout, Xadd, nullptr, 32768, 1024, 1024, lg & 7, lg >> 3, lds);
}

// ---------------- launcher ----------------------------------------------------
extern "C" void kernel_launch(void* const* d_in, const int* in_sizes, int n_in,
                              void* d_out, int out_size, void* d_ws, size_t ws_size,
                              hipStream_t stream) {
  const float* x      = (const float*)d_in[0];
  const float* xf     = (const float*)d_in[1];
  const float* emb    = (const float*)d_in[2];
  const int*   cond   = (const int*)d_in[4];
  const float* ln_x_g = (const float*)d_in[5];
  const float* ln_x_b = (const float*)d_in[6];
  const float* ln_t_g = (const float*)d_in[7];
  const float* ln_t_b = (const float*)d_in[8];
  const float* Wq     = (const float*)d_in[9];
  const float* bq     = (const float*)d_in[10];
  const float* Wk     = (const float*)d_in[11];
  const float* bk     = (const float*)d_in[12];
  const float* Wv     = (const float*)d_in[13];
  const float* bv     = (const float*)d_in[14];
  const float* We     = (const float*)d_in[15];
  const float* be     = (const float*)d_in[16];
  const float* ln_y_g = (const float*)d_in[17];
  const float* ln_y_b = (const float*)d_in[18];
  const float* Wo     = (const float*)d_in[19];
  const float* bo     = (const float*)d_in[20];
  float* out = (float*)d_out;

  unsigned char* ws = (unsigned char*)d_ws;
  size_t off = 0;
  auto take = [&](size_t n){ unsigned char* p = ws + off; off += (n + 255) & ~(size_t)255; return p; };
  unsigned char* r1    = take(67108864);   // xln bf16 -> h bf16
  unsigned char* qb    = take(67108864);   // q bf16 -> y bf16 (in place)
  unsigned char* xfn   = take(12582912);   // LN(xf) bf16
  unsigned char* kb    = take(16777216);   // k bf16 [8192][1024]
  unsigned char* vtb   = take(16777216);   // v^T pre-swizzled bf16
  unsigned char* wqt   = take(2097152);
  unsigned char* wkvt  = take(3145728);
  unsigned char* wot   = take(2097152);
  unsigned char* eo    = take(262144);
  unsigned char* bkv   = take(8192);
  unsigned char* epart = take(4194304);    // [16][32][2048] fp32

  dim3 blk(256);
  // 1) LN (4 rows/block, dead-batch skip) + weight prep   [56 VGPR]
  prep_ln<<<13832, blk, 0, stream>>>(x, xf, ln_x_g, ln_x_b, ln_t_g, ln_t_b,
      (unsigned short*)r1, (unsigned short*)xfn,
      Wq, Wk, Wv, Wo, bk, bv,
      (unsigned short*)wqt, (unsigned short*)wkvt, (unsigned short*)wot, (float*)bkv,
      cond);
  // 2) Q-proj + KV-proj (fused V->vt) + embgemm tail, dead-batch skips
  qkv<<<3200, blk, 0, stream>>>(r1, (const unsigned short*)wqt, bq, qb,
      xfn, (const unsigned short*)wkvt, (const float*)bkv, kb, vtb, cond,
      emb, We, (float*)epart);
  // 3) attention (y bf16 in place over q) + embred tail
  attn64<<<8224, blk, 0, stream>>>(qb, kb, 2048, vtb, cond, (unsigned short*)qb,
      (const float*)epart, be, (float*)eo);
  // 4) stylization -> h bf16 (overwrites r1)
  styl<<<32768, blk, 0, stream>>>((const unsigned short*)qb, ln_y_g, ln_y_b, (const float*)eo, (unsigned short*)r1);
  // 5) O-projection + residual
  gemmO<<<2048, blk, 0, stream>>>(r1, wot, bo, out, x);
}